// Round 1
// baseline (248.667 us; speedup 1.0000x reference)
//
#include <hip/hip_runtime.h>

#define N_TOK 65536
#define DIM   64
#define K_EMB 512
#define BT    64      // tokens per block
#define BK    64      // embeddings per k-tile
#define LSTR  68      // LDS row stride (floats): 16B-aligned rows, 2-way bank aliasing only

// d_out layout (fp32, concatenated in return order):
//   [0)            encodings_ste  N_TOK*DIM      = 4194304
//   [4194304)      idx (as float) N_TOK          = 65536
//   [4259840)      sq_distances   K_EMB*N_TOK    = 33554432
//   [37814272)     loss           1

__global__ void vq_zero_loss(float* loss) {
    if (threadIdx.x == 0) *loss = 0.0f;
}

__global__ __launch_bounds__(256, 2) void vq_main(
    const float* __restrict__ x,     // [N_TOK, DIM]
    const float* __restrict__ emb,   // [K_EMB, DIM]
    float* __restrict__ out_enc,     // [N_TOK, DIM]
    float* __restrict__ out_idx,     // [N_TOK] (float-valued indices)
    float* __restrict__ out_sq,      // [K_EMB, N_TOK]
    float* __restrict__ out_loss)    // [1]
{
    __shared__ float Xs[BT * LSTR];
    __shared__ float Es[BK * LSTR];
    __shared__ float xnorm[BT];
    __shared__ float enorm[BK];
    __shared__ float redv[16 * BT];
    __shared__ int   redi[16 * BT];
    __shared__ int   besti_sh[BT];

    const int tid = threadIdx.x;
    const int tx  = tid & 15;   // token group: tokens tx + 16*s
    const int ty  = tid >> 4;   // emb group:   codes  ty + 16*t
    const int n0  = blockIdx.x * BT;

    // ---- load X tile (coalesced), compute xnorm ----
    {
        const int c = tx * 4;
        #pragma unroll
        for (int p = 0; p < 4; ++p) {
            const int r = ty + 16 * p;
            float4 v = *(const float4*)&x[(size_t)(n0 + r) * DIM + c];
            *(float4*)&Xs[r * LSTR + c] = v;
        }
    }
    __syncthreads();
    if (tid < BT) {
        float s = 0.0f;
        #pragma unroll
        for (int dc = 0; dc < DIM; dc += 4) {
            float4 v = *(const float4*)&Xs[tid * LSTR + dc];
            s += v.x * v.x + v.y * v.y + v.z * v.z + v.w * v.w;
        }
        xnorm[tid] = s;
    }

    float bestv[4];
    int   bidx[4];
    #pragma unroll
    for (int s = 0; s < 4; ++s) { bestv[s] = 3.4e38f; bidx[s] = 0; }

    for (int kt = 0; kt < K_EMB / BK; ++kt) {
        const int k0 = kt * BK;
        __syncthreads();   // protect Es reuse (and publish xnorm on first iter)
        {
            const int c = tx * 4;
            #pragma unroll
            for (int p = 0; p < 4; ++p) {
                const int r = ty + 16 * p;
                float4 v = *(const float4*)&emb[(size_t)(k0 + r) * DIM + c];
                *(float4*)&Es[r * LSTR + c] = v;
            }
        }
        __syncthreads();
        if (tid < BK) {
            float s = 0.0f;
            #pragma unroll
            for (int dc = 0; dc < DIM; dc += 4) {
                float4 v = *(const float4*)&Es[tid * LSTR + dc];
                s += v.x * v.x + v.y * v.y + v.z * v.z + v.w * v.w;
            }
            enorm[tid] = s;
        }
        __syncthreads();

        // ---- 4x4 register-tile dot products ----
        float acc[4][4];
        #pragma unroll
        for (int t = 0; t < 4; ++t)
            #pragma unroll
            for (int s = 0; s < 4; ++s) acc[t][s] = 0.0f;

        #pragma unroll
        for (int dc = 0; dc < DIM; dc += 4) {
            float4 xa[4], ea[4];
            #pragma unroll
            for (int s = 0; s < 4; ++s)
                xa[s] = *(const float4*)&Xs[(tx + 16 * s) * LSTR + dc];
            #pragma unroll
            for (int t = 0; t < 4; ++t)
                ea[t] = *(const float4*)&Es[(ty + 16 * t) * LSTR + dc];
            #pragma unroll
            for (int t = 0; t < 4; ++t)
                #pragma unroll
                for (int s = 0; s < 4; ++s)
                    acc[t][s] += ea[t].x * xa[s].x + ea[t].y * xa[s].y +
                                 ea[t].z * xa[s].z + ea[t].w * xa[s].w;
        }

        // ---- emit sq block + running argmin ----
        #pragma unroll
        for (int t = 0; t < 4; ++t) {
            const int k  = k0 + ty + 16 * t;
            const float en = enorm[ty + 16 * t];
            #pragma unroll
            for (int s = 0; s < 4; ++s) {
                const int n = tx + 16 * s;
                // match reference order: (xnorm + enorm) - 2*dot
                const float sq = (xnorm[n] + en) - 2.0f * acc[t][s];
                out_sq[(size_t)k * N_TOK + n0 + n] = sq;
                if (sq < bestv[s]) { bestv[s] = sq; bidx[s] = k; }  // first-min kept (k ascending per thread)
            }
        }
    }

    // ---- argmin reduction across the 16 code-groups per token ----
    #pragma unroll
    for (int s = 0; s < 4; ++s) {
        redv[ty * BT + tx + 16 * s] = bestv[s];
        redi[ty * BT + tx + 16 * s] = bidx[s];
    }
    __syncthreads();
    if (tid < BT) {
        float bv = redv[tid];
        int   bi = redi[tid];
        #pragma unroll
        for (int j = 1; j < 16; ++j) {
            const float v = redv[j * BT + tid];
            const int   i = redi[j * BT + tid];
            if (v < bv || (v == bv && i < bi)) { bv = v; bi = i; }
        }
        besti_sh[tid] = bi;
        out_idx[n0 + tid] = (float)bi;   // indices <= 511: exact in fp32
    }
    __syncthreads();

    // ---- epilogue: gather codes, write encodings (coalesced), loss partial ----
    float lp = 0.0f;
    {
        const int c = tx * 4;
        #pragma unroll
        for (int p = 0; p < 4; ++p) {
            const int r  = ty + 16 * p;
            const int bi = besti_sh[r];
            float4 e  = *(const float4*)&emb[(size_t)bi * DIM + c];
            *(float4*)&out_enc[(size_t)(n0 + r) * DIM + c] = e;
            float4 xv = *(const float4*)&Xs[r * LSTR + c];
            const float d0 = e.x - xv.x, d1 = e.y - xv.y, d2 = e.z - xv.z, d3 = e.w - xv.w;
            lp += d0 * d0 + d1 * d1 + d2 * d2 + d3 * d3;
        }
    }
    #pragma unroll
    for (int off = 32; off > 0; off >>= 1) lp += __shfl_down(lp, off, 64);
    if ((tid & 63) == 0) {
        // loss = (1 + beta) * mean((enc - x)^2); beta = 0.25
        atomicAdd(out_loss, lp * (1.25f / 4194304.0f));
    }
}

extern "C" void kernel_launch(void* const* d_in, const int* in_sizes, int n_in,
                              void* d_out, int out_size, void* d_ws, size_t ws_size,
                              hipStream_t stream) {
    const float* x   = (const float*)d_in[0];
    const float* emb = (const float*)d_in[1];
    float* out       = (float*)d_out;

    float* out_enc  = out;                // 4194304
    float* out_idx  = out + 4194304;      // 65536
    float* out_sq   = out + 4259840;      // 33554432
    float* out_loss = out + 37814272;     // 1

    vq_zero_loss<<<1, 64, 0, stream>>>(out_loss);
    vq_main<<<N_TOK / BT, 256, 0, stream>>>(x, emb, out_enc, out_idx, out_sq, out_loss);
}

// Round 2
// 238.784 us; speedup vs baseline: 1.0414x; 1.0414x over previous
//
#include <hip/hip_runtime.h>

#define N_TOK 65536
#define DIM   64
#define K_EMB 512
#define BT    64               // tokens per block
#define NQ    4                // code-quarters (one per wave)
#define KPT   (K_EMB / NQ)     // 128 codes per thread
#define LSTR  68               // X-stage LDS row stride

// d_out layout (fp32, concatenated in return order):
//   [0)         encodings_ste  N_TOK*DIM   = 4194304
//   [4194304)   idx (as float) N_TOK       = 65536
//   [4259840)   sq_distances   K_EMB*N_TOK = 33554432
//   [37814272)  loss           1

// Prep: e-norms for all 512 codes into d_ws; zero the loss accumulator.
__global__ void vq_prep(const float* __restrict__ emb,
                        float* __restrict__ enorm,
                        float* __restrict__ loss) {
    const int k = blockIdx.x * blockDim.x + threadIdx.x;
    if (k == 0) *loss = 0.0f;
    if (k < K_EMB) {
        const float4* e4 = (const float4*)(emb + (size_t)k * DIM);
        float s = 0.0f;
        #pragma unroll
        for (int i = 0; i < 16; ++i) {
            float4 v = e4[i];
            s += v.x * v.x + v.y * v.y + v.z * v.z + v.w * v.w;
        }
        enorm[k] = s;
    }
}

__global__ __launch_bounds__(256, 4) void vq_main(
    const float* __restrict__ x,      // [N_TOK, DIM]
    const float* __restrict__ emb,    // [K_EMB, DIM]
    const float* __restrict__ enorm,  // [K_EMB] precomputed |e|^2
    float* __restrict__ out_enc,      // [N_TOK, DIM]
    float* __restrict__ out_idx,      // [N_TOK]
    float* __restrict__ out_sq,       // [K_EMB, N_TOK]
    float* __restrict__ out_loss)     // [1]
{
    __shared__ float Xs[BT * LSTR];
    __shared__ float redv[NQ * BT];
    __shared__ int   redi[NQ * BT];
    __shared__ int   besti[BT];

    const int tid = threadIdx.x;
    const int tx  = tid & 63;                                   // token within tile (= lane)
    const int q   = __builtin_amdgcn_readfirstlane(tid >> 6);   // wave-uniform code quarter
    const int n0  = blockIdx.x * BT;

    // ---- stage X tile coalesced into LDS (once) ----
    {
        const int c = (tid & 15) * 4;
        const int r = tid >> 4;
        #pragma unroll
        for (int p = 0; p < 4; ++p) {
            const int rr = r + 16 * p;
            float4 v = *(const float4*)&x[(size_t)(n0 + rr) * DIM + c];
            *(float4*)&Xs[rr * LSTR + c] = v;
        }
    }
    __syncthreads();

    // ---- each thread pulls its full token row into VGPRs (one-time) ----
    float xr[DIM];
    #pragma unroll
    for (int c = 0; c < 16; ++c) {
        float4 v = *(const float4*)&Xs[tx * LSTR + c * 4];
        xr[4 * c]     = v.x;
        xr[4 * c + 1] = v.y;
        xr[4 * c + 2] = v.z;
        xr[4 * c + 3] = v.w;
    }
    float x0 = 0.f, x1 = 0.f, x2 = 0.f, x3 = 0.f;
    #pragma unroll
    for (int c = 0; c < 16; ++c) {
        x0 = fmaf(xr[4 * c],     xr[4 * c],     x0);
        x1 = fmaf(xr[4 * c + 1], xr[4 * c + 1], x1);
        x2 = fmaf(xr[4 * c + 2], xr[4 * c + 2], x2);
        x3 = fmaf(xr[4 * c + 3], xr[4 * c + 3], x3);
    }
    const float xn = (x0 + x1) + (x2 + x3);

    // ---- scan this quarter's 128 codes: E from scalar loads (SGPRs) ----
    const int k0 = q * KPT;
    float bestv = 3.4e38f;
    int   bidx  = 0;
    float* sqp = out_sq + (size_t)k0 * N_TOK + (n0 + tx);

    for (int j = 0; j < KPT; ++j) {
        const int k = k0 + j;
        const float* ek = emb + ((size_t)k << 6);   // wave-uniform -> s_load
        float d0 = 0.f, d1 = 0.f, d2 = 0.f, d3 = 0.f;
        #pragma unroll
        for (int c = 0; c < 16; ++c) {
            d0 = fmaf(ek[4 * c],     xr[4 * c],     d0);
            d1 = fmaf(ek[4 * c + 1], xr[4 * c + 1], d1);
            d2 = fmaf(ek[4 * c + 2], xr[4 * c + 2], d2);
            d3 = fmaf(ek[4 * c + 3], xr[4 * c + 3], d3);
        }
        const float dot = (d0 + d1) + (d2 + d3);
        const float sq  = (xn + enorm[k]) - 2.0f * dot;
        *sqp = sq;
        sqp += N_TOK;
        if (sq < bestv) { bestv = sq; bidx = k; }   // strict < keeps first min (k ascending)
    }

    // ---- argmin across the NQ quarters of each token ----
    redv[q * BT + tx] = bestv;
    redi[q * BT + tx] = bidx;
    __syncthreads();
    if (tid < BT) {
        float bv = redv[tid];
        int   bi = redi[tid];
        #pragma unroll
        for (int j = 1; j < NQ; ++j) {
            const float v = redv[j * BT + tid];
            const int   i = redi[j * BT + tid];
            if (v < bv || (v == bv && i < bi)) { bv = v; bi = i; }
        }
        besti[tid] = bi;
        out_idx[n0 + tid] = (float)bi;   // indices <= 511: exact in fp32
    }
    __syncthreads();

    // ---- epilogue: gather codes, write encodings (coalesced), loss partial ----
    float lp = 0.0f;
    {
        const int c = (tid & 15) * 4;
        const int r = tid >> 4;
        #pragma unroll
        for (int p = 0; p < 4; ++p) {
            const int rr = r + 16 * p;
            const int bi = besti[rr];
            float4 e  = *(const float4*)&emb[(size_t)bi * DIM + c];
            *(float4*)&out_enc[(size_t)(n0 + rr) * DIM + c] = e;
            float4 xv = *(const float4*)&Xs[rr * LSTR + c];
            const float a0 = e.x - xv.x, a1 = e.y - xv.y, a2 = e.z - xv.z, a3 = e.w - xv.w;
            lp += a0 * a0 + a1 * a1 + a2 * a2 + a3 * a3;
        }
    }
    #pragma unroll
    for (int off = 32; off > 0; off >>= 1) lp += __shfl_down(lp, off, 64);
    if ((tid & 63) == 0) {
        // loss = (1 + beta) * mean((enc - x)^2); beta = 0.25
        atomicAdd(out_loss, lp * (1.25f / 4194304.0f));
    }
}

extern "C" void kernel_launch(void* const* d_in, const int* in_sizes, int n_in,
                              void* d_out, int out_size, void* d_ws, size_t ws_size,
                              hipStream_t stream) {
    const float* x   = (const float*)d_in[0];
    const float* emb = (const float*)d_in[1];
    float* out       = (float*)d_out;
    float* enorm     = (float*)d_ws;   // 512 floats

    float* out_enc  = out;                // 4194304
    float* out_idx  = out + 4194304;      // 65536
    float* out_sq   = out + 4259840;      // 33554432
    float* out_loss = out + 37814272;     // 1

    vq_prep<<<2, 256, 0, stream>>>(emb, enorm, out_loss);
    vq_main<<<N_TOK / BT, 256, 0, stream>>>(x, emb, enorm,
                                            out_enc, out_idx, out_sq, out_loss);
}

// Round 3
// 237.290 us; speedup vs baseline: 1.0479x; 1.0063x over previous
//
#include <hip/hip_runtime.h>

#define N_TOK 65536
#define DIM   64
#define K_EMB 512
#define BT    64      // tokens per block
#define ESTR  72      // halfs per E row in LDS (144 B: 16B-aligned, 2-way bank alias = free)
#define XSTR  72
#define MARGIN 0.125f // > 2x worst-case f16-split sq error (~0.062)

typedef _Float16 half8 __attribute__((ext_vector_type(8)));
typedef _Float16 half4 __attribute__((ext_vector_type(4)));
typedef float    f32x4 __attribute__((ext_vector_type(4)));

// d_out layout (fp32, concatenated in return order):
//   [0)         encodings_ste  N_TOK*DIM   = 4194304
//   [4194304)   idx (as float) N_TOK       = 65536
//   [4259840)   sq_distances   K_EMB*N_TOK = 33554432
//   [37814272)  loss           1

// Prep: fp32 e-norms for all 512 codes into d_ws (bit-identical to R2); zero loss.
__global__ void vq_prep(const float* __restrict__ emb,
                        float* __restrict__ enorm,
                        float* __restrict__ loss) {
    const int k = blockIdx.x * blockDim.x + threadIdx.x;
    if (k == 0) *loss = 0.0f;
    if (k < K_EMB) {
        const float4* e4 = (const float4*)(emb + (size_t)k * DIM);
        float s = 0.0f;
        #pragma unroll
        for (int i = 0; i < 16; ++i) {
            float4 v = e4[i];
            s += v.x * v.x + v.y * v.y + v.z * v.z + v.w * v.w;
        }
        enorm[k] = s;
    }
}

__global__ __launch_bounds__(256) void vq_main(
    const float* __restrict__ x,      // [N_TOK, DIM]
    const float* __restrict__ emb,    // [K_EMB, DIM]
    const float* __restrict__ enorm,  // [K_EMB] fp32 |e|^2 (from prep)
    float* __restrict__ out_enc,
    float* __restrict__ out_idx,
    float* __restrict__ out_sq,
    float* __restrict__ out_loss)
{
    __shared__ __align__(16) _Float16 Eh[K_EMB * ESTR];  // 73.7 KB
    __shared__ __align__(16) _Float16 Xh[BT * XSTR];     // 9.2 KB
    __shared__ __align__(16) _Float16 Xl[BT * XSTR];     // 9.2 KB
    __shared__ float en_s[K_EMB];
    __shared__ float xn_s[BT];
    __shared__ int   ccnt[BT];
    __shared__ int   cand[BT * 8];
    __shared__ int   besti[BT];

    const int tid  = threadIdx.x;
    const int n0   = blockIdx.x * BT;
    const int lane = tid & 63;
    const int w    = tid >> 6;      // wave id = token-tile
    const int lr   = lane & 15;
    const int quad = lane >> 4;

    // ================= phase 0: staging =================
    // Whole codebook -> f16 LDS, coalesced (8192 float4).
    #pragma unroll 4
    for (int i = 0; i < 32; ++i) {
        const int idx = i * 256 + tid;
        float4 v = ((const float4*)emb)[idx];
        const int row = idx >> 4, c4 = idx & 15;
        half4 h = { (_Float16)v.x, (_Float16)v.y, (_Float16)v.z, (_Float16)v.w };
        *(half4*)&Eh[row * ESTR + c4 * 4] = h;
    }
    // X tile -> f16 hi/lo LDS (1024 float4).
    #pragma unroll
    for (int i = 0; i < 4; ++i) {
        const int idx = i * 256 + tid;
        float4 v = ((const float4*)(x + (size_t)n0 * DIM))[idx];
        const int row = idx >> 4, c4 = idx & 15;
        _Float16 hx = (_Float16)v.x, hy = (_Float16)v.y,
                 hz = (_Float16)v.z, hw = (_Float16)v.w;
        half4 hh = { hx, hy, hz, hw };
        half4 hl = { (_Float16)(v.x - (float)hx), (_Float16)(v.y - (float)hy),
                     (_Float16)(v.z - (float)hz), (_Float16)(v.w - (float)hw) };
        *(half4*)&Xh[row * XSTR + c4 * 4] = hh;
        *(half4*)&Xl[row * XSTR + c4 * 4] = hl;
    }
    if (tid < 128) ((float4*)en_s)[tid] = ((const float4*)enorm)[tid];
    if (tid < BT) {
        ccnt[tid] = 0;
        // xn: replicate R2's quad-pairwise formula exactly.
        const float4* xr = (const float4*)(x + (size_t)(n0 + tid) * DIM);
        float x0 = 0.f, x1 = 0.f, x2 = 0.f, x3 = 0.f;
        #pragma unroll
        for (int c = 0; c < 16; ++c) {
            float4 v = xr[c];
            x0 = fmaf(v.x, v.x, x0);
            x1 = fmaf(v.y, v.y, x1);
            x2 = fmaf(v.z, v.z, x2);
            x3 = fmaf(v.w, v.w, x3);
        }
        xn_s[tid] = (x0 + x1) + (x2 + x3);
    }
    __syncthreads();

    // ================= phase 1: MFMA sweep =================
    // GEMM D[m=code][n=token] = E(codes x K) * X^T(K x tokens), 16x16x32 f16.
    // A frag: lane holds E[code = kt*16 + lr][k = quad*8 + j]
    // B frag: lane holds X[token = w*16 + lr][k = quad*8 + j]  (loop-invariant!)
    // C frag: lane reg holds D[code = kt*16 + quad*4 + reg][token = w*16 + lr]
    const int tok = w * 16 + lr;
    const half8 bxh0 = *(const half8*)&Xh[tok * XSTR + quad * 8];
    const half8 bxh1 = *(const half8*)&Xh[tok * XSTR + 32 + quad * 8];
    const half8 bxl0 = *(const half8*)&Xl[tok * XSTR + quad * 8];
    const half8 bxl1 = *(const half8*)&Xl[tok * XSTR + 32 + quad * 8];
    const float xnl  = xn_s[tok];

    float m1 = 3.4e38f, m2 = 3.4e38f, m3 = 3.4e38f;
    int   i1 = 0, i2 = 0, i3 = 0;

    #pragma unroll 2
    for (int kt = 0; kt < 32; ++kt) {
        const int erow = (kt * 16 + lr) * ESTR;
        const half8 a0 = *(const half8*)&Eh[erow + quad * 8];
        const half8 a1 = *(const half8*)&Eh[erow + 32 + quad * 8];
        f32x4 acc = { 0.f, 0.f, 0.f, 0.f };
        acc = __builtin_amdgcn_mfma_f32_16x16x32_f16(a0, bxh0, acc, 0, 0, 0);
        acc = __builtin_amdgcn_mfma_f32_16x16x32_f16(a1, bxh1, acc, 0, 0, 0);
        acc = __builtin_amdgcn_mfma_f32_16x16x32_f16(a0, bxl0, acc, 0, 0, 0);
        acc = __builtin_amdgcn_mfma_f32_16x16x32_f16(a1, bxl1, acc, 0, 0, 0);

        const f32x4 e4 = *(const f32x4*)&en_s[kt * 16 + quad * 4];
        #pragma unroll
        for (int reg = 0; reg < 4; ++reg) {
            const int   ki = kt * 16 + quad * 4 + reg;
            const float sq = (xnl + e4[reg]) - 2.0f * acc[reg];
            __builtin_nontemporal_store(sq, &out_sq[(size_t)ki * N_TOK + n0 + tok]);
            // 3-deep running min; ascending ki + strict < keeps first occurrence.
            if (sq < m3) {
                if (sq < m2) {
                    if (sq < m1) { m3 = m2; i3 = i2; m2 = m1; i2 = i1; m1 = sq; i1 = ki; }
                    else         { m3 = m2; i3 = i2; m2 = sq; i2 = ki; }
                } else           { m3 = sq; i3 = ki; }
            }
        }
    }

    // ================= phase 2: candidates + exact repair =================
    float mstar = m1;
    mstar = fminf(mstar, __shfl_xor(mstar, 16, 64));
    mstar = fminf(mstar, __shfl_xor(mstar, 32, 64));
    const float thr = mstar + MARGIN;
    if (m1 <= thr) { int p = atomicAdd(&ccnt[tok], 1); if (p < 8) cand[tok * 8 + p] = i1; }
    if (m2 <= thr) { int p = atomicAdd(&ccnt[tok], 1); if (p < 8) cand[tok * 8 + p] = i2; }
    if (m3 <= thr) { int p = atomicAdd(&ccnt[tok], 1); if (p < 8) cand[tok * 8 + p] = i3; }
    __syncthreads();

    if (tid < BT) {
        const int cnt = min(ccnt[tid], 8);
        float bv = 3.4e38f;
        int   bi = 0x7fffffff;
        const float4* xr = (const float4*)(x + (size_t)(n0 + tid) * DIM);
        for (int c = 0; c < cnt; ++c) {
            const int k = cand[tid * 8 + c];
            const float4* ep = (const float4*)(emb + (size_t)k * DIM);
            // exact fp32 recompute, bit-identical to R2's passing arithmetic
            float d0 = 0.f, d1 = 0.f, d2 = 0.f, d3 = 0.f;
            #pragma unroll
            for (int j = 0; j < 16; ++j) {
                float4 xv = xr[j], ev = ep[j];
                d0 = fmaf(ev.x, xv.x, d0);
                d1 = fmaf(ev.y, xv.y, d1);
                d2 = fmaf(ev.z, xv.z, d2);
                d3 = fmaf(ev.w, xv.w, d3);
            }
            const float dot = (d0 + d1) + (d2 + d3);
            const float sq  = (xn_s[tid] + en_s[k]) - 2.0f * dot;
            if (sq < bv || (sq == bv && k < bi)) { bv = sq; bi = k; }
        }
        besti[tid] = bi;
        out_idx[n0 + tid] = (float)bi;   // <= 511: exact in fp32
    }
    __syncthreads();

    // ================= phase 3: enc/ste + loss (R2-identical) =================
    float lp = 0.0f;
    {
        const int c = (tid & 15) * 4;
        const int r = tid >> 4;
        #pragma unroll
        for (int p = 0; p < 4; ++p) {
            const int rr = r + 16 * p;
            const int bi = besti[rr];
            float4 e  = *(const float4*)&emb[(size_t)bi * DIM + c];
            *(float4*)&out_enc[(size_t)(n0 + rr) * DIM + c] = e;
            float4 xv = *(const float4*)&x[(size_t)(n0 + rr) * DIM + c];
            const float a0 = e.x - xv.x, a1 = e.y - xv.y, a2 = e.z - xv.z, a3 = e.w - xv.w;
            lp += a0 * a0 + a1 * a1 + a2 * a2 + a3 * a3;
        }
    }
    #pragma unroll
    for (int off = 32; off > 0; off >>= 1) lp += __shfl_down(lp, off, 64);
    if ((tid & 63) == 0) {
        atomicAdd(out_loss, lp * (1.25f / 4194304.0f));  // (1+beta)*mean, beta=0.25
    }
}

extern "C" void kernel_launch(void* const* d_in, const int* in_sizes, int n_in,
                              void* d_out, int out_size, void* d_ws, size_t ws_size,
                              hipStream_t stream) {
    const float* x   = (const float*)d_in[0];
    const float* emb = (const float*)d_in[1];
    float* out       = (float*)d_out;
    float* enorm     = (float*)d_ws;   // 512 floats

    float* out_enc  = out;                // 4194304
    float* out_idx  = out + 4194304;      // 65536
    float* out_sq   = out + 4259840;      // 33554432
    float* out_loss = out + 37814272;     // 1

    vq_prep<<<2, 256, 0, stream>>>(emb, enorm, out_loss);
    vq_main<<<N_TOK / BT, 256, 0, stream>>>(x, emb, enorm,
                                            out_enc, out_idx, out_sq, out_loss);
}

// Round 4
// 235.226 us; speedup vs baseline: 1.0571x; 1.0088x over previous
//
#include <hip/hip_runtime.h>

#define N_TOK 65536
#define DIM   64
#define K_EMB 512
#define BT    64      // tokens per block (4 waves x 16)
#define MARGIN 0.125f // > 2x worst-case f16-split sq error (~0.062)

typedef _Float16 half8 __attribute__((ext_vector_type(8)));
typedef _Float16 half4 __attribute__((ext_vector_type(4)));
typedef float    f32x4 __attribute__((ext_vector_type(4)));

// d_out layout (fp32, concatenated in return order):
//   [0)         encodings_ste  N_TOK*DIM   = 4194304
//   [4194304)   idx (as float) N_TOK       = 65536
//   [4259840)   sq_distances   K_EMB*N_TOK = 33554432
//   [37814272)  loss           1
//
// d_ws layout: [0) enorm 512 f32 (2 KB) | [2048) eh f16 codebook [512][64] (64 KB)

// Prep: f16 codebook + fp32 e-norms into ws; zero loss. 32x256 threads.
__global__ void vq_prep(const float* __restrict__ emb,
                        float* __restrict__ enorm,
                        _Float16* __restrict__ eh,
                        float* __restrict__ loss) {
    const int gid = blockIdx.x * blockDim.x + threadIdx.x;   // 8192 threads
    // coalesced f32 -> f16 conversion, 4 elems/thread
    {
        float4 v = ((const float4*)emb)[gid];
        half4 h = { (_Float16)v.x, (_Float16)v.y, (_Float16)v.z, (_Float16)v.w };
        ((half4*)eh)[gid] = h;
    }
    if (gid == 0) *loss = 0.0f;
    if (gid < K_EMB) {
        const float4* e4 = (const float4*)(emb + (size_t)gid * DIM);
        float s = 0.0f;
        #pragma unroll
        for (int i = 0; i < 16; ++i) {
            float4 v = e4[i];
            s += v.x * v.x + v.y * v.y + v.z * v.z + v.w * v.w;
        }
        enorm[gid] = s;
    }
}

__global__ __launch_bounds__(256, 4) void vq_main(
    const float* __restrict__ x,      // [N_TOK, DIM]
    const float* __restrict__ emb,    // [K_EMB, DIM] fp32 (exact repair + epilogue)
    const float* __restrict__ enorm,  // [K_EMB] fp32 |e|^2
    const _Float16* __restrict__ eh,  // [K_EMB][DIM] f16 codebook (L2-resident)
    float* __restrict__ out_enc,
    float* __restrict__ out_idx,
    float* __restrict__ out_sq,
    float* __restrict__ out_loss)
{
    __shared__ float en_s[K_EMB];
    __shared__ float xn_s[BT];
    __shared__ int   ccnt[BT];
    __shared__ int   cand[BT * 8];
    __shared__ int   besti[BT];

    const int tid  = threadIdx.x;
    const int n0   = blockIdx.x * BT;
    const int lane = tid & 63;
    const int w    = tid >> 6;      // wave id = 16-token tile
    const int lr   = lane & 15;
    const int quad = lane >> 4;
    const int tok  = w * 16 + lr;

    // ================= phase 0: small staging =================
    if (tid < 128) ((float4*)en_s)[tid] = ((const float4*)enorm)[tid];
    if (tid < BT) {
        ccnt[tid] = 0;
        // xn with R2/R3's exact quad-pairwise formula (used by exact repair).
        const float4* xr = (const float4*)(x + (size_t)(n0 + tid) * DIM);
        float x0 = 0.f, x1 = 0.f, x2 = 0.f, x3 = 0.f;
        #pragma unroll
        for (int c = 0; c < 16; ++c) {
            float4 v = xr[c];
            x0 = fmaf(v.x, v.x, x0);
            x1 = fmaf(v.y, v.y, x1);
            x2 = fmaf(v.z, v.z, x2);
            x3 = fmaf(v.w, v.w, x3);
        }
        xn_s[tid] = (x0 + x1) + (x2 + x3);
    }

    // ---- B-frags straight from global: lane owns X[tok][quad*8..+8] and [+32..] ----
    half8 bxh0, bxl0, bxh1, bxl1;
    {
        const float4* xrow = (const float4*)(x + (size_t)(n0 + tok) * DIM);
        float4 v0 = xrow[quad * 2];
        float4 v1 = xrow[quad * 2 + 1];
        float4 v2 = xrow[8 + quad * 2];
        float4 v3 = xrow[8 + quad * 2 + 1];
        float f0[8] = { v0.x, v0.y, v0.z, v0.w, v1.x, v1.y, v1.z, v1.w };
        float f1[8] = { v2.x, v2.y, v2.z, v2.w, v3.x, v3.y, v3.z, v3.w };
        #pragma unroll
        for (int i = 0; i < 8; ++i) {
            _Float16 h = (_Float16)f0[i];
            bxh0[i] = h; bxl0[i] = (_Float16)(f0[i] - (float)h);
            _Float16 g = (_Float16)f1[i];
            bxh1[i] = g; bxl1[i] = (_Float16)(f1[i] - (float)g);
        }
    }
    __syncthreads();
    const float xnl = xn_s[tok];

    // ================= phase 1: MFMA sweep (A from L2-resident f16 codebook) ==
    // A frag: lane holds E[code = kt*16 + lr][k = quad*8 + j]
    // C frag: lane reg holds D[code = kt*16 + quad*4 + reg][token = tok]
    const _Float16* ebase = eh + (size_t)lr * DIM + quad * 8;   // + kt*16*DIM per tile

    float m1 = 3.4e38f, m2 = 3.4e38f, m3 = 3.4e38f;
    int   i1 = 0, i2 = 0, i3 = 0;

    half8 a0 = *(const half8*)(ebase);
    half8 a1 = *(const half8*)(ebase + 32);

    for (int kt = 0; kt < 32; ++kt) {
        // prefetch next tile's A-frags (clamped; re-read of last row is an L2 hit)
        const int ktn = kt < 31 ? kt + 1 : 31;
        half8 na0 = *(const half8*)(ebase + (size_t)ktn * 16 * DIM);
        half8 na1 = *(const half8*)(ebase + (size_t)ktn * 16 * DIM + 32);

        f32x4 acc = { 0.f, 0.f, 0.f, 0.f };
        acc = __builtin_amdgcn_mfma_f32_16x16x32_f16(a0, bxh0, acc, 0, 0, 0);
        acc = __builtin_amdgcn_mfma_f32_16x16x32_f16(a1, bxh1, acc, 0, 0, 0);
        acc = __builtin_amdgcn_mfma_f32_16x16x32_f16(a0, bxl0, acc, 0, 0, 0);
        acc = __builtin_amdgcn_mfma_f32_16x16x32_f16(a1, bxl1, acc, 0, 0, 0);

        const f32x4 e4 = *(const f32x4*)&en_s[kt * 16 + quad * 4];
        #pragma unroll
        for (int reg = 0; reg < 4; ++reg) {
            const int   ki = kt * 16 + quad * 4 + reg;
            const float sq = (xnl + e4[reg]) - 2.0f * acc[reg];
            __builtin_nontemporal_store(sq, &out_sq[(size_t)ki * N_TOK + n0 + tok]);
            // 3-deep running min; ascending ki + strict < keeps first occurrence.
            if (sq < m3) {
                if (sq < m2) {
                    if (sq < m1) { m3 = m2; i3 = i2; m2 = m1; i2 = i1; m1 = sq; i1 = ki; }
                    else         { m3 = m2; i3 = i2; m2 = sq; i2 = ki; }
                } else           { m3 = sq; i3 = ki; }
            }
        }
        a0 = na0; a1 = na1;
    }

    // ================= phase 2: candidates + exact fp32 repair =================
    float mstar = m1;
    mstar = fminf(mstar, __shfl_xor(mstar, 16, 64));
    mstar = fminf(mstar, __shfl_xor(mstar, 32, 64));
    const float thr = mstar + MARGIN;
    if (m1 <= thr) { int p = atomicAdd(&ccnt[tok], 1); if (p < 8) cand[tok * 8 + p] = i1; }
    if (m2 <= thr) { int p = atomicAdd(&ccnt[tok], 1); if (p < 8) cand[tok * 8 + p] = i2; }
    if (m3 <= thr) { int p = atomicAdd(&ccnt[tok], 1); if (p < 8) cand[tok * 8 + p] = i3; }
    __syncthreads();

    if (tid < BT) {
        const int cnt = min(ccnt[tid], 8);
        float bv = 3.4e38f;
        int   bi = 0x7fffffff;
        const float4* xr = (const float4*)(x + (size_t)(n0 + tid) * DIM);
        for (int c = 0; c < cnt; ++c) {
            const int k = cand[tid * 8 + c];
            const float4* ep = (const float4*)(emb + (size_t)k * DIM);
            // exact fp32 recompute, bit-identical to R2's passing arithmetic
            float d0 = 0.f, d1 = 0.f, d2 = 0.f, d3 = 0.f;
            #pragma unroll
            for (int j = 0; j < 16; ++j) {
                float4 xv = xr[j], ev = ep[j];
                d0 = fmaf(ev.x, xv.x, d0);
                d1 = fmaf(ev.y, xv.y, d1);
                d2 = fmaf(ev.z, xv.z, d2);
                d3 = fmaf(ev.w, xv.w, d3);
            }
            const float dot = (d0 + d1) + (d2 + d3);
            const float sq  = (xn_s[tid] + en_s[k]) - 2.0f * dot;
            if (sq < bv || (sq == bv && k < bi)) { bv = sq; bi = k; }
        }
        besti[tid] = bi;
        out_idx[n0 + tid] = (float)bi;   // <= 511: exact in fp32
    }
    __syncthreads();

    // ================= phase 3: enc/ste + loss =================
    float lp = 0.0f;
    {
        const int c = (tid & 15) * 4;
        const int r = tid >> 4;
        #pragma unroll
        for (int p = 0; p < 4; ++p) {
            const int rr = r + 16 * p;
            const int bi = besti[rr];
            float4 e  = *(const float4*)&emb[(size_t)bi * DIM + c];
            *(float4*)&out_enc[(size_t)(n0 + rr) * DIM + c] = e;
            float4 xv = *(const float4*)&x[(size_t)(n0 + rr) * DIM + c];
            const float a0 = e.x - xv.x, a1 = e.y - xv.y, a2 = e.z - xv.z, a3 = e.w - xv.w;
            lp += a0 * a0 + a1 * a1 + a2 * a2 + a3 * a3;
        }
    }
    #pragma unroll
    for (int off = 32; off > 0; off >>= 1) lp += __shfl_down(lp, off, 64);
    if ((tid & 63) == 0) {
        atomicAdd(out_loss, lp * (1.25f / 4194304.0f));  // (1+beta)*mean, beta=0.25
    }
}

extern "C" void kernel_launch(void* const* d_in, const int* in_sizes, int n_in,
                              void* d_out, int out_size, void* d_ws, size_t ws_size,
                              hipStream_t stream) {
    const float* x   = (const float*)d_in[0];
    const float* emb = (const float*)d_in[1];
    float* out       = (float*)d_out;
    float* enorm     = (float*)d_ws;                       // 512 f32
    _Float16* eh     = (_Float16*)((char*)d_ws + 2048);    // 512*64 f16 (64 KB)

    float* out_enc  = out;                // 4194304
    float* out_idx  = out + 4194304;      // 65536
    float* out_sq   = out + 4259840;      // 33554432
    float* out_loss = out + 37814272;     // 1

    vq_prep<<<32, 256, 0, stream>>>(emb, enorm, eh, out_loss);
    vq_main<<<N_TOK / BT, 256, 0, stream>>>(x, emb, enorm, eh,
                                            out_enc, out_idx, out_sq, out_loss);
}